// Round 2
// baseline (483.121 us; speedup 1.0000x reference)
//
#include <hip/hip_runtime.h>
#include <math.h>

typedef unsigned short u16;
typedef unsigned int u32;
typedef __bf16 bf16x8 __attribute__((ext_vector_type(8)));
typedef float f32x4 __attribute__((ext_vector_type(4)));

__device__ __forceinline__ u16 f2b(float f) {
    u32 u = __float_as_uint(f);
    return (u16)((u + 0x7FFFu + ((u >> 16) & 1u)) >> 16);
}
__device__ __forceinline__ float b2f(u16 h) {
    return __uint_as_float(((u32)h) << 16);
}

// async global->LDS, 16B per lane. LDS dest is wave-uniform base + lane*16.
#define GLL16(gp, lp)                                                          \
    __builtin_amdgcn_global_load_lds(                                          \
        (__attribute__((address_space(1))) void*)(const_cast<u16*>(gp)),       \
        (__attribute__((address_space(3))) void*)(lp), 16, 0, 0)

// ---------------------------------------------------------------------------
// 256x256 8-phase NT GEMM (T2+T3+T4+T5). 8 waves (2M x 4N), BK=64,
// LDS 128 KiB (2 dbuf x (A 32K + B 32K)).
//
// Phase = (rq, k-half): 4 A-frag + 4 B-frag ds_read_b128 (no duplicate reads:
// 24 reads / K-tile / wave), 16 MFMA. Two barriers per phase, lgkmcnt(0)+
// sched_barrier pin (rule #18), setprio(1) around the MFMA cluster (T5).
//
// Counted vmcnt (T4): next K-tile staged as B0,B1 | B2,B3 | A0,A2 | A1,A3
// across phases 0-3. Waits: phase1 end vmcnt(4) (retire old A1,A3 needed by
// phase2), phase3 end vmcnt(2) (retire B*,A0,A2 needed by next tile's
// phase0; A1,A3 stay in flight). Never drains to 0 in steady state; every
// load gets >=2.5 phases of MFMA cover.
//
// LDS swizzle (T2): logical k-chunk kc stored at physical chunk
// kc ^ ((row>>1)&7) via inverse-swizzled GLOBAL source (GLL dest stays
// linear, rule #21); fragment ds_read applies the same XOR. 0 conflicts
// (verified round 1).
//
// MODE 0: 2-D row x col grid, XCD-swizzled by row tile (QKV / proj), bz=0.
// MODE 1: batch x tril-tile grid (wei): bz=n&15, t=n>>4 in 0..9 lower-tri.
// MODE 2: batch x full 4x4 grid (attn): kEnd=(by+1)*256 causal truncation.
// EPI  0: +bias, pair-rotate -> bf16 (k/q/vT split; v stored transposed)
//      1: softplus(scale*x) causal-masked -> bf16
//      2: inverse pair-rotate -> bf16
//      3: +bias -> f32
// ---------------------------------------------------------------------------
template <int EPI, int MODE>
__global__ __launch_bounds__(512, 2) void gemm256(
    const u16* __restrict__ A, long long sAz,
    const u16* __restrict__ B, long long sBz,
    void* __restrict__ D0, void* __restrict__ D1, void* __restrict__ D2,
    long long sDz,
    const float* __restrict__ bias0, const float* __restrict__ bias1,
    const float* __restrict__ bias2,
    const u32* __restrict__ cossin,
    int N, int K, float scale, int WB)
{
    extern __shared__ u16 lds[];
    u16* const As = lds;                    // [2][4 chunks][64 rows][64]
    u16* const Bs = lds + 2 * 256 * 64;

    int bx, by, bz;
    if (MODE == 0) {
        const int n = blockIdx.x;
        const int xcd = n & 7, m = n >> 3;
        by = xcd + 8 * (m / WB);
        bx = m % WB;
        bz = 0;
    } else if (MODE == 1) {
        const int n = blockIdx.x;
        bz = n & 15;
        const int t = n >> 4;               // 0..9 lower-triangular tile
        by = (t >= 1) + (t >= 3) + (t >= 6);
        bx = t - ((by * (by + 1)) >> 1);
    } else {
        const int n = blockIdx.x;
        bz = n & 15;
        const int t = n >> 4;               // 0..15
        by = t >> 2;
        bx = t & 3;
    }
    const int r0 = by * 256, c0 = bx * 256;

    const int kEnd = (MODE == 2) ? (((by + 1) * 256) < K ? ((by + 1) * 256) : K) : K;
    const int nkt = kEnd >> 6;

    const int tid = threadIdx.x;
    const int lane = tid & 63, wave = tid >> 6;
    const int wr = wave >> 2, wc = wave & 3;

    const u16* __restrict__ Ab = A + (long long)bz * sAz + (long long)r0 * K;
    const u16* __restrict__ Bb = B + (long long)bz * sBz + (long long)c0 * K;

    // staging: thread t fills LDS linearly (row = chunk*64 + tid/8, k-chunk =
    // tid&7); global source k-chunk pre-swizzled (inverse of the read XOR).
    const int srow = tid >> 3;
    const int skc8 = (((tid & 7) ^ ((tid >> 4) & 7))) * 8;

    // fragment-read constants (read XOR = (lane>>1)&7, matches stage inverse)
    const int lr = lane & 15;
    const int xr = (lane >> 1) & 7;
    const int kof0 = (((lane >> 4) + 0) ^ xr) * 8;   // k-half 0
    const int kof1 = (((lane >> 4) + 4) ^ xr) * 8;   // k-half 1

    f32x4 acc[8][4];
    #pragma unroll
    for (int i = 0; i < 8; ++i)
        #pragma unroll
        for (int j = 0; j < 4; ++j)
            acc[i][j] = (f32x4){0.f, 0.f, 0.f, 0.f};

    // prologue: stage K-tile 0 into buffer 0, in the steady-state issue order
    #pragma unroll
    for (int r = 0; r < 4; ++r)
        GLL16(Bb + (long long)(r * 64 + srow) * K + skc8, Bs + r * 4096 + tid * 8);
    GLL16(Ab + (long long)(0 * 64 + srow) * K + skc8, As + 0 * 4096 + tid * 8);
    GLL16(Ab + (long long)(2 * 64 + srow) * K + skc8, As + 2 * 4096 + tid * 8);
    GLL16(Ab + (long long)(1 * 64 + srow) * K + skc8, As + 1 * 4096 + tid * 8);
    GLL16(Ab + (long long)(3 * 64 + srow) * K + skc8, As + 3 * 4096 + tid * 8);
    asm volatile("s_waitcnt vmcnt(2)" ::: "memory");   // A1,A3 stay in flight
    __builtin_amdgcn_s_barrier();

    for (int kt = 0; kt < nkt; ++kt) {
        const int buf = kt & 1;
        const u16* asb = As + buf * 16384;
        const u16* bsb = Bs + buf * 16384;
        u16* asn = As + (buf ^ 1) * 16384;
        u16* bsn = Bs + (buf ^ 1) * 16384;
        const long long kbn = (long long)(kt + 1) * 64 + skc8;
        const bool pf = (kt + 1 < nkt);
        #pragma unroll
        for (int ph = 0; ph < 4; ++ph) {
            const int rq = ph >> 1;
            const int kof = (ph & 1) ? kof1 : kof0;
            const int ab0 = wr * 128 + rq * 64;
            bf16x8 a[4], b[4];
            #pragma unroll
            for (int i = 0; i < 4; ++i)
                a[i] = *(const bf16x8*)&asb[(ab0 + i * 16 + lr) * 64 + kof];
            #pragma unroll
            for (int j = 0; j < 4; ++j)
                b[j] = *(const bf16x8*)&bsb[(wc * 64 + j * 16 + lr) * 64 + kof];
            if (pf) {
                if (ph == 0) {
                    GLL16(Bb + (long long)(0 * 64 + srow) * K + kbn, bsn + 0 * 4096 + tid * 8);
                    GLL16(Bb + (long long)(1 * 64 + srow) * K + kbn, bsn + 1 * 4096 + tid * 8);
                } else if (ph == 1) {
                    GLL16(Bb + (long long)(2 * 64 + srow) * K + kbn, bsn + 2 * 4096 + tid * 8);
                    GLL16(Bb + (long long)(3 * 64 + srow) * K + kbn, bsn + 3 * 4096 + tid * 8);
                } else if (ph == 2) {
                    GLL16(Ab + (long long)(0 * 64 + srow) * K + kbn, asn + 0 * 4096 + tid * 8);
                    GLL16(Ab + (long long)(2 * 64 + srow) * K + kbn, asn + 2 * 4096 + tid * 8);
                } else {
                    GLL16(Ab + (long long)(1 * 64 + srow) * K + kbn, asn + 1 * 4096 + tid * 8);
                    GLL16(Ab + (long long)(3 * 64 + srow) * K + kbn, asn + 3 * 4096 + tid * 8);
                }
            }
            __builtin_amdgcn_s_barrier();
            asm volatile("s_waitcnt lgkmcnt(0)" ::: "memory");
            __builtin_amdgcn_sched_barrier(0);   // rule #18: pin MFMA after wait
            __builtin_amdgcn_s_setprio(1);
            #pragma unroll
            for (int i = 0; i < 4; ++i)
                #pragma unroll
                for (int j = 0; j < 4; ++j)
                    acc[rq * 4 + i][j] = __builtin_amdgcn_mfma_f32_16x16x32_bf16(
                        a[i], b[j], acc[rq * 4 + i][j], 0, 0, 0);
            __builtin_amdgcn_s_setprio(0);
            if (ph == 1) {
                if (pf) asm volatile("s_waitcnt vmcnt(4)" ::: "memory");
                else    asm volatile("s_waitcnt vmcnt(0)" ::: "memory");
            } else if (ph == 3 && pf) {
                asm volatile("s_waitcnt vmcnt(2)" ::: "memory");
            }
            __builtin_amdgcn_s_barrier();
        }
    }

    // output routing (uniform per block)
    void* Dp = D0;
    const float* bp_ = bias0;
    int ldD = N, cbase = c0, sel = 0;
    if (EPI == 0) {
        sel = bx >> 2;                 // 4 tiles of 256 per 1024-col group
        Dp  = (sel == 0) ? D0 : (sel == 1) ? D1 : D2;
        bp_ = (sel == 0) ? bias0 : (sel == 1) ? bias1 : bias2;
        ldD = 1024;
        cbase = c0 & 1023;
    }

    // epilogue: C/D layout col=lane&15, row=(lane>>4)*4+reg
    const int rl = (lane >> 4) * 4, cl = lane & 15;
    const int grb = r0 + wr * 128;
    const int gcb = cbase + wc * 64;

    if (EPI == 0 && sel == 2) {
        // v group: bias + rotate + TRANSPOSED store into vT[b][c][t]
        #pragma unroll
        for (int ai = 0; ai < 8; ++ai) {
            #pragma unroll
            for (int bj = 0; bj < 4; ++bj) {
                const int gr0 = grb + ai * 16 + rl;       // 4-aligned t base
                const int gcd = gcb + bj * 16 + cl;       // v column
                u16 pk[4];
                #pragma unroll
                for (int v = 0; v < 4; ++v) {
                    const int gr = gr0 + v;
                    float my = acc[ai][bj][v] + bp_[gcd];
                    float other = __shfl_xor(my, 1);
                    u32 csn = cossin[(long long)gr * 512 + (gcd >> 1)];
                    float cs = b2f((u16)(csn & 0xffff)), sn = b2f((u16)(csn >> 16));
                    float res = (gcd & 1) ? (sn * other + cs * my)
                                          : (cs * my - sn * other);
                    pk[v] = f2b(res);
                }
                const int bb = gr0 >> 10, tt = gr0 & 1023;
                u16* dst = (u16*)Dp + ((((long long)bb << 10) + gcd) << 10) + tt;
                uint2 pw;
                pw.x = (u32)pk[0] | ((u32)pk[1] << 16);
                pw.y = (u32)pk[2] | ((u32)pk[3] << 16);
                *(uint2*)dst = pw;
            }
        }
        return;
    }

    #pragma unroll
    for (int ai = 0; ai < 8; ++ai) {
        #pragma unroll
        for (int bj = 0; bj < 4; ++bj) {
            const int gr0 = grb + ai * 16 + rl;
            const int gcd = gcb + bj * 16 + cl;
            #pragma unroll
            for (int v = 0; v < 4; ++v) {
                const int gr = gr0 + v;
                float val = acc[ai][bj][v];
                const long long o = (long long)bz * sDz + (long long)gr * ldD + gcd;
                if (EPI == 0) {
                    float my = val + bp_[gcd];
                    float other = __shfl_xor(my, 1);
                    u32 csn = cossin[(long long)gr * 512 + (gcd >> 1)];
                    float cs = b2f((u16)(csn & 0xffff)), sn = b2f((u16)(csn >> 16));
                    float res = (gcd & 1) ? (sn * other + cs * my)
                                          : (cs * my - sn * other);
                    ((u16*)Dp)[o] = f2b(res);
                } else if (EPI == 1) {
                    float xs = val * scale;
                    float r = (gcd <= gr) ? ((xs > 15.f) ? xs : log1pf(__expf(xs))) : 0.f;
                    ((u16*)Dp)[o] = f2b(r);
                } else if (EPI == 2) {
                    float my = val;
                    float other = __shfl_xor(my, 1);
                    u32 csn = cossin[((long long)((bz << 10) + gr)) * 512 + (gcd >> 1)];
                    float cs = b2f((u16)(csn & 0xffff)), sn = b2f((u16)(csn >> 16));
                    float res = (gcd & 1) ? (cs * my - sn * other)
                                          : (cs * my + sn * other);
                    ((u16*)Dp)[o] = f2b(res);
                } else {
                    ((float*)Dp)[o] = val + bp_[gcd];
                }
            }
        }
    }
}

// ---------------------------------------------------------------------------
// fp32 -> bf16 conversion, vectorized x4
// ---------------------------------------------------------------------------
__global__ void f2b_kern(const float* __restrict__ in, u16* __restrict__ out, int n4) {
    int i = blockIdx.x * blockDim.x + threadIdx.x;
    if (i >= n4) return;
    float4 f = ((const float4*)in)[i];
    uint2 o;
    o.x = (u32)f2b(f.x) | ((u32)f2b(f.y) << 16);
    o.y = (u32)f2b(f.z) | ((u32)f2b(f.w) << 16);
    ((uint2*)out)[i] = o;
}

// 4 weight matrices in one launch (blockIdx.y selects)
__global__ void f2b_w4(const float* __restrict__ a, const float* __restrict__ b,
                       const float* __restrict__ c, const float* __restrict__ d,
                       u16* __restrict__ oa, u16* __restrict__ ob,
                       u16* __restrict__ oc, u16* __restrict__ od, int n4) {
    int i = blockIdx.x * blockDim.x + threadIdx.x;
    if (i >= n4) return;
    const float* src = (blockIdx.y == 0) ? a : (blockIdx.y == 1) ? b
                     : (blockIdx.y == 2) ? c : d;
    u16* dst = (blockIdx.y == 0) ? oa : (blockIdx.y == 1) ? ob
             : (blockIdx.y == 2) ? oc : od;
    float4 f = ((const float4*)src)[i];
    uint2 o;
    o.x = (u32)f2b(f.x) | ((u32)f2b(f.y) << 16);
    o.y = (u32)f2b(f.z) | ((u32)f2b(f.w) << 16);
    ((uint2*)dst)[i] = o;
}

// ---------------------------------------------------------------------------
// Angle suffix-sum (angle[t] = sum_{s>=t} emb[idx[s]]) in 3 phases; phase 3
// emits packed bf16 {cos, sin}.
// ---------------------------------------------------------------------------
#define TT 1024
#define CC2 512
#define NCH 32
#define CL 32

__global__ void angle_partial(const int* __restrict__ idx, const float* __restrict__ emb,
                              float* __restrict__ partial) {
    int b = blockIdx.x >> 5, ch = blockIdx.x & 31;
    int c = threadIdx.x;               // 0..511
    float s = 0.f;
    int tb = ch * CL;
    for (int t = 0; t < CL; t++) {
        int row = idx[b * TT + tb + t];
        s += emb[(long long)row * CC2 + c];
    }
    partial[((long long)b * NCH + ch) * CC2 + c] = s;
}

__global__ void angle_scan(float* __restrict__ partial) {
    int b = blockIdx.x, c = threadIdx.x;
    float run = 0.f;
    for (int ch = NCH - 1; ch >= 0; ch--) {
        long long o = ((long long)b * NCH + ch) * CC2 + c;
        float p = partial[o];
        partial[o] = run;              // exclusive suffix (chunks after this one)
        run += p;
    }
}

__global__ void angle_final(const int* __restrict__ idx, const float* __restrict__ emb,
                            const float* __restrict__ partial,
                            u32* __restrict__ cossin) {
    int b = blockIdx.x >> 5, ch = blockIdx.x & 31;
    int c = threadIdx.x;
    float run = partial[((long long)b * NCH + ch) * CC2 + c];
    for (int t = CL - 1; t >= 0; t--) {
        int tt = ch * CL + t;
        int row = idx[b * TT + tt];
        run += emb[(long long)row * CC2 + c];
        float sn, cs;
        __sincosf(run, &sn, &cs);
        cossin[((long long)b * TT + tt) * CC2 + c] = (u32)f2b(cs) | ((u32)f2b(sn) << 16);
    }
}

// ---------------------------------------------------------------------------
extern "C" void kernel_launch(void* const* d_in, const int* in_sizes, int n_in,
                              void* d_out, int out_size, void* d_ws, size_t ws_size,
                              hipStream_t stream) {
    const int Bn = 16, T = 1024, C = 1024;
    const long long TC = (long long)T * C;
    const size_t nx = (size_t)Bn * T * C;          // 16,777,216
    const size_t npairs = nx / 2;                  // 8,388,608

    const float* x   = (const float*)d_in[0];
    const int*   idx = (const int*)d_in[1];
    const float* Wk  = (const float*)d_in[2];
    const float* bk  = (const float*)d_in[3];
    const float* Wq  = (const float*)d_in[4];
    const float* bq  = (const float*)d_in[5];
    const float* Wv  = (const float*)d_in[6];
    const float* bv  = (const float*)d_in[7];
    const float* Wp  = (const float*)d_in[8];
    const float* bp  = (const float*)d_in[9];
    const float* emb = (const float*)d_in[10];
    float* out = (float*)d_out;

    // one-time: allow 128 KiB dynamic LDS on the 256^2 kernels
    static bool s_attr = false;
    if (!s_attr) {
        auto* k0 = gemm256<0, 0>;
        auto* k1 = gemm256<1, 1>;
        auto* k2 = gemm256<2, 2>;
        auto* k3 = gemm256<3, 0>;
        (void)hipFuncSetAttribute(reinterpret_cast<const void*>(k0),
                                  hipFuncAttributeMaxDynamicSharedMemorySize, 131072);
        (void)hipFuncSetAttribute(reinterpret_cast<const void*>(k1),
                                  hipFuncAttributeMaxDynamicSharedMemorySize, 131072);
        (void)hipFuncSetAttribute(reinterpret_cast<const void*>(k2),
                                  hipFuncAttributeMaxDynamicSharedMemorySize, 131072);
        (void)hipFuncSetAttribute(reinterpret_cast<const void*>(k3),
                                  hipFuncAttributeMaxDynamicSharedMemorySize, 131072);
        s_attr = true;
    }

    // workspace (~171 MB)
    u16* xb  = (u16*)d_ws;          // x bf16; aliased as wei after QKV
    u16* kb  = xb + nx;             // k (rotated by QKV epilogue)
    u16* qb  = kb + nx;             // q (rotated); y after attn GEMM
    u16* vT  = qb + nx;             // v rotated+transposed [B][C][T]
    u32* cossin = (u32*)(vT + nx);  // [B][T][512] packed bf16 {cos,sin}
    u16* Wall = (u16*)(cossin + npairs);           // [3072][1024] = Wk|Wq|Wv
    u16* Wpb  = Wall + (size_t)3 * C * C;
    float* partial = (float*)(Wpb + (size_t)C * C);  // [B][32][512]
    u16* wei = xb;                  // alias (x dead after QKV)

    // 1) conversions to bf16
    f2b_kern<<<(int)(nx / 4 / 256), 256, 0, stream>>>(x, xb, (int)(nx / 4));
    f2b_w4<<<dim3(C * C / 4 / 256, 4), 256, 0, stream>>>(
        Wk, Wq, Wv, Wp, Wall, Wall + (size_t)C * C, Wall + (size_t)2 * C * C, Wpb,
        C * C / 4);

    // 2) angle suffix-sum -> packed cos/sin
    angle_partial<<<Bn * NCH, 512, 0, stream>>>(idx, emb, partial);
    angle_scan<<<Bn, 512, 0, stream>>>(partial);
    angle_final<<<Bn * NCH, 512, 0, stream>>>(idx, emb, partial, cossin);

    // 3) fused QKV projection: M=16384, N=3072, K=1024; 64x12 tiles.
    gemm256<0, 0><<<768, 512, 131072, stream>>>(
        xb, 0, Wall, 0, kb, qb, vT, 0, bk, bq, bv, cossin,
        3 * C, C, 1.f, 12);

    // 4) wei = softplus(k @ q^T / 32), causal: 16 batches x 10 tril tiles
    gemm256<1, 1><<<160, 512, 131072, stream>>>(
        kb, TC, qb, TC, wei, nullptr, nullptr, (long long)T * T,
        nullptr, nullptr, nullptr, nullptr, T, C, 0.03125f, 0);

    // 5) attn = wei @ v, inverse-rotation epilogue -> y (qb);
    //    16 batches x 16 tiles, K truncated at (by+1)*256 (causal)
    gemm256<2, 2><<<256, 512, 131072, stream>>>(
        wei, (long long)T * T, vT, (long long)C * T, qb, nullptr, nullptr, TC,
        nullptr, nullptr, nullptr, cossin, C, T, 1.f, 0);

    // 6) final projection -> f32 out: 64x4 tiles.
    gemm256<3, 0><<<256, 512, 131072, stream>>>(
        qb, 0, Wpb, 0, out, nullptr, nullptr, 0, bp, nullptr, nullptr, nullptr,
        C, C, 1.f, 4);
}

// Round 3
// 461.465 us; speedup vs baseline: 1.0469x; 1.0469x over previous
//
#include <hip/hip_runtime.h>
#include <math.h>

typedef unsigned short u16;
typedef unsigned int u32;
typedef __bf16 bf16x8 __attribute__((ext_vector_type(8)));
typedef float f32x4 __attribute__((ext_vector_type(4)));

__device__ __forceinline__ u16 f2b(float f) {
    u32 u = __float_as_uint(f);
    return (u16)((u + 0x7FFFu + ((u >> 16) & 1u)) >> 16);
}
__device__ __forceinline__ float b2f(u16 h) {
    return __uint_as_float(((u32)h) << 16);
}

// async global->LDS, 16B per lane. LDS dest is wave-uniform base + lane*16.
#define GLL16(gp, lp)                                                          \
    __builtin_amdgcn_global_load_lds(                                          \
        (__attribute__((address_space(1))) void*)(const_cast<u16*>(gp)),       \
        (__attribute__((address_space(3))) void*)(lp), 16, 0, 0)

// ---------------------------------------------------------------------------
// 256x256 NT GEMM, 4 phases/K-tile, ONE barrier per phase. 8 waves (2M x 4N),
// BK=64, LDS 128 KiB (2 dbuf x (A 32K + B 32K)).
//
// Phase p = (rq = p>>1, kh = p&1). Reads: rq=0 phases load 4 A-frags + 4
// B-frags; rq=1 phases load 4 A-frags and REUSE the B-frags cached in regs
// (B read once per K-tile). MFMA 16 per phase.
//
// Publish points (cross-wave GLL->LDS visibility): each wave's vmcnt followed
// by the phase-end s_barrier. ph1-end: vmcnt(4) retires prev-tile A1,A3
// (needed by ph2/ph3 reads). ph3-end: vmcnt(2) retires next-tile B0..B3,
// A0,A2 (needed by next ph0/ph1); next-tile A1,A3 stay in flight. Loads are
// never drained to 0 in steady state. The pre-MFMA barrier of the classic
// 8-phase template is REMOVED: it publishes nothing (no vmcnt precedes it;
// ds_reads are wave-private), and without it waves stagger ds_read/MFMA/GLL
// phases against each other naturally.
//
// LDS swizzle (T2): logical k-chunk kc stored at physical chunk
// kc ^ ((row>>1)&7) via inverse-swizzled GLOBAL source (GLL dest stays
// linear, rule #21); fragment ds_read applies the same XOR. 0 conflicts
// (verified round 1).
//
// MODE 0: 2-D row x col grid, XCD-swizzled by row tile (QKV / proj), bz=0.
// MODE 1: batch x tril-tile grid (wei): bz=n&15, t=n>>4 in 0..9 lower-tri.
// MODE 2: batch x full 4x4 grid (attn): kEnd=(by+1)*256 causal truncation.
// EPI  0: +bias, pair-rotate -> bf16 (k/q/vT split; v stored transposed)
//      1: softplus(scale*x) causal-masked -> bf16
//      2: inverse pair-rotate -> bf16
//      3: +bias -> f32
// ---------------------------------------------------------------------------
template <int EPI, int MODE>
__global__ __launch_bounds__(512, 2) void gemm256(
    const u16* __restrict__ A, long long sAz,
    const u16* __restrict__ B, long long sBz,
    void* __restrict__ D0, void* __restrict__ D1, void* __restrict__ D2,
    long long sDz,
    const float* __restrict__ bias0, const float* __restrict__ bias1,
    const float* __restrict__ bias2,
    const u32* __restrict__ cossin,
    int N, int K, float scale, int WB)
{
    extern __shared__ u16 lds[];
    u16* const As = lds;                    // [2][4 chunks][64 rows][64]
    u16* const Bs = lds + 2 * 256 * 64;

    int bx, by, bz;
    if (MODE == 0) {
        const int n = blockIdx.x;
        const int xcd = n & 7, m = n >> 3;
        by = xcd + 8 * (m / WB);
        bx = m % WB;
        bz = 0;
    } else if (MODE == 1) {
        const int n = blockIdx.x;
        bz = n & 15;
        const int t = n >> 4;               // 0..9 lower-triangular tile
        by = (t >= 1) + (t >= 3) + (t >= 6);
        bx = t - ((by * (by + 1)) >> 1);
    } else {
        const int n = blockIdx.x;
        bz = n & 15;
        const int t = n >> 4;               // 0..15
        by = t >> 2;
        bx = t & 3;
    }
    const int r0 = by * 256, c0 = bx * 256;

    const int kEnd = (MODE == 2) ? (((by + 1) * 256) < K ? ((by + 1) * 256) : K) : K;
    const int nkt = kEnd >> 6;

    const int tid = threadIdx.x;
    const int lane = tid & 63, wave = tid >> 6;
    const int wr = wave >> 2, wc = wave & 3;

    const u16* __restrict__ Ab = A + (long long)bz * sAz + (long long)r0 * K;
    const u16* __restrict__ Bb = B + (long long)bz * sBz + (long long)c0 * K;

    // staging: thread t fills LDS linearly (row = chunk*64 + tid/8, k-chunk =
    // tid&7); global source k-chunk pre-swizzled (inverse of the read XOR).
    const int srow = tid >> 3;
    const int skc8 = (((tid & 7) ^ ((tid >> 4) & 7))) * 8;

    // fragment-read constants (read XOR = (lane>>1)&7, matches stage inverse)
    const int lr = lane & 15;
    const int xr = (lane >> 1) & 7;
    const int kof0 = (((lane >> 4) + 0) ^ xr) * 8;   // k-half 0
    const int kof1 = (((lane >> 4) + 4) ^ xr) * 8;   // k-half 1

    f32x4 acc[8][4];
    #pragma unroll
    for (int i = 0; i < 8; ++i)
        #pragma unroll
        for (int j = 0; j < 4; ++j)
            acc[i][j] = (f32x4){0.f, 0.f, 0.f, 0.f};

    // prologue: stage K-tile 0 into buffer 0, in the steady-state issue order
    #pragma unroll
    for (int r = 0; r < 4; ++r)
        GLL16(Bb + (long long)(r * 64 + srow) * K + skc8, Bs + r * 4096 + tid * 8);
    GLL16(Ab + (long long)(0 * 64 + srow) * K + skc8, As + 0 * 4096 + tid * 8);
    GLL16(Ab + (long long)(2 * 64 + srow) * K + skc8, As + 2 * 4096 + tid * 8);
    GLL16(Ab + (long long)(1 * 64 + srow) * K + skc8, As + 1 * 4096 + tid * 8);
    GLL16(Ab + (long long)(3 * 64 + srow) * K + skc8, As + 3 * 4096 + tid * 8);
    asm volatile("s_waitcnt vmcnt(2)" ::: "memory");   // A1,A3 stay in flight
    __builtin_amdgcn_s_barrier();

    for (int kt = 0; kt < nkt; ++kt) {
        const int buf = kt & 1;
        const u16* asb = As + buf * 16384;
        const u16* bsb = Bs + buf * 16384;
        u16* asn = As + (buf ^ 1) * 16384;
        u16* bsn = Bs + (buf ^ 1) * 16384;
        const long long kbn = (long long)(kt + 1) * 64 + skc8;
        const bool pf = (kt + 1 < nkt);
        bf16x8 bc[2][4];                     // B frags cached across rq pair
        #pragma unroll
        for (int ph = 0; ph < 4; ++ph) {
            const int rq = ph >> 1, kh = ph & 1;
            const int kof = kh ? kof1 : kof0;
            const int ab0 = wr * 128 + rq * 64;
            bf16x8 a[4];
            #pragma unroll
            for (int i = 0; i < 4; ++i)
                a[i] = *(const bf16x8*)&asb[(ab0 + i * 16 + lr) * 64 + kof];
            if (rq == 0) {
                #pragma unroll
                for (int j = 0; j < 4; ++j)
                    bc[kh][j] = *(const bf16x8*)&bsb[(wc * 64 + j * 16 + lr) * 64 + kof];
            }
            if (pf) {
                if (ph == 0) {
                    GLL16(Bb + (long long)(0 * 64 + srow) * K + kbn, bsn + 0 * 4096 + tid * 8);
                    GLL16(Bb + (long long)(1 * 64 + srow) * K + kbn, bsn + 1 * 4096 + tid * 8);
                } else if (ph == 1) {
                    GLL16(Bb + (long long)(2 * 64 + srow) * K + kbn, bsn + 2 * 4096 + tid * 8);
                    GLL16(Bb + (long long)(3 * 64 + srow) * K + kbn, bsn + 3 * 4096 + tid * 8);
                } else if (ph == 2) {
                    GLL16(Ab + (long long)(0 * 64 + srow) * K + kbn, asn + 0 * 4096 + tid * 8);
                    GLL16(Ab + (long long)(2 * 64 + srow) * K + kbn, asn + 2 * 4096 + tid * 8);
                } else {
                    GLL16(Ab + (long long)(1 * 64 + srow) * K + kbn, asn + 1 * 4096 + tid * 8);
                    GLL16(Ab + (long long)(3 * 64 + srow) * K + kbn, asn + 3 * 4096 + tid * 8);
                }
            }
            asm volatile("s_waitcnt lgkmcnt(0)" ::: "memory");
            __builtin_amdgcn_sched_barrier(0);   // rule #18: pin MFMA after wait
            __builtin_amdgcn_s_setprio(1);
            #pragma unroll
            for (int i = 0; i < 4; ++i)
                #pragma unroll
                for (int j = 0; j < 4; ++j)
                    acc[rq * 4 + i][j] = __builtin_amdgcn_mfma_f32_16x16x32_bf16(
                        a[i], bc[kh][j], acc[rq * 4 + i][j], 0, 0, 0);
            __builtin_amdgcn_s_setprio(0);
            if (ph == 1) {
                if (pf) asm volatile("s_waitcnt vmcnt(4)" ::: "memory");
                else    asm volatile("s_waitcnt vmcnt(0)" ::: "memory");
            } else if (ph == 3 && pf) {
                asm volatile("s_waitcnt vmcnt(2)" ::: "memory");
            }
            __builtin_amdgcn_s_barrier();
        }
    }

    // output routing (uniform per block)
    void* Dp = D0;
    const float* bp_ = bias0;
    int ldD = N, cbase = c0, sel = 0;
    if (EPI == 0) {
        sel = bx >> 2;                 // 4 tiles of 256 per 1024-col group
        Dp  = (sel == 0) ? D0 : (sel == 1) ? D1 : D2;
        bp_ = (sel == 0) ? bias0 : (sel == 1) ? bias1 : bias2;
        ldD = 1024;
        cbase = c0 & 1023;
    }

    // epilogue: C/D layout col=lane&15, row=(lane>>4)*4+reg
    const int rl = (lane >> 4) * 4, cl = lane & 15;
    const int grb = r0 + wr * 128;
    const int gcb = cbase + wc * 64;

    if (EPI == 0 && sel == 2) {
        // v group: bias + rotate + TRANSPOSED store into vT[b][c][t]
        #pragma unroll
        for (int ai = 0; ai < 8; ++ai) {
            #pragma unroll
            for (int bj = 0; bj < 4; ++bj) {
                const int gr0 = grb + ai * 16 + rl;       // 4-aligned t base
                const int gcd = gcb + bj * 16 + cl;       // v column
                u16 pk[4];
                #pragma unroll
                for (int v = 0; v < 4; ++v) {
                    const int gr = gr0 + v;
                    float my = acc[ai][bj][v] + bp_[gcd];
                    float other = __shfl_xor(my, 1);
                    u32 csn = cossin[(long long)gr * 512 + (gcd >> 1)];
                    float cs = b2f((u16)(csn & 0xffff)), sn = b2f((u16)(csn >> 16));
                    float res = (gcd & 1) ? (sn * other + cs * my)
                                          : (cs * my - sn * other);
                    pk[v] = f2b(res);
                }
                const int bb = gr0 >> 10, tt = gr0 & 1023;
                u16* dst = (u16*)Dp + ((((long long)bb << 10) + gcd) << 10) + tt;
                uint2 pw;
                pw.x = (u32)pk[0] | ((u32)pk[1] << 16);
                pw.y = (u32)pk[2] | ((u32)pk[3] << 16);
                *(uint2*)dst = pw;
            }
        }
        return;
    }

    #pragma unroll
    for (int ai = 0; ai < 8; ++ai) {
        #pragma unroll
        for (int bj = 0; bj < 4; ++bj) {
            const int gr0 = grb + ai * 16 + rl;
            const int gcd = gcb + bj * 16 + cl;
            #pragma unroll
            for (int v = 0; v < 4; ++v) {
                const int gr = gr0 + v;
                float val = acc[ai][bj][v];
                const long long o = (long long)bz * sDz + (long long)gr * ldD + gcd;
                if (EPI == 0) {
                    float my = val + bp_[gcd];
                    float other = __shfl_xor(my, 1);
                    u32 csn = cossin[(long long)gr * 512 + (gcd >> 1)];
                    float cs = b2f((u16)(csn & 0xffff)), sn = b2f((u16)(csn >> 16));
                    float res = (gcd & 1) ? (sn * other + cs * my)
                                          : (cs * my - sn * other);
                    ((u16*)Dp)[o] = f2b(res);
                } else if (EPI == 1) {
                    float xs = val * scale;
                    float r = (gcd <= gr) ? ((xs > 15.f) ? xs : log1pf(__expf(xs))) : 0.f;
                    ((u16*)Dp)[o] = f2b(r);
                } else if (EPI == 2) {
                    float my = val;
                    float other = __shfl_xor(my, 1);
                    u32 csn = cossin[((long long)((bz << 10) + gr)) * 512 + (gcd >> 1)];
                    float cs = b2f((u16)(csn & 0xffff)), sn = b2f((u16)(csn >> 16));
                    float res = (gcd & 1) ? (cs * my - sn * other)
                                          : (cs * my + sn * other);
                    ((u16*)Dp)[o] = f2b(res);
                } else {
                    ((float*)Dp)[o] = val + bp_[gcd];
                }
            }
        }
    }
}

// ---------------------------------------------------------------------------
// fp32 -> bf16 conversion, vectorized x4
// ---------------------------------------------------------------------------
__global__ void f2b_kern(const float* __restrict__ in, u16* __restrict__ out, int n4) {
    int i = blockIdx.x * blockDim.x + threadIdx.x;
    if (i >= n4) return;
    float4 f = ((const float4*)in)[i];
    uint2 o;
    o.x = (u32)f2b(f.x) | ((u32)f2b(f.y) << 16);
    o.y = (u32)f2b(f.z) | ((u32)f2b(f.w) << 16);
    ((uint2*)out)[i] = o;
}

// 4 weight matrices in one launch (blockIdx.y selects)
__global__ void f2b_w4(const float* __restrict__ a, const float* __restrict__ b,
                       const float* __restrict__ c, const float* __restrict__ d,
                       u16* __restrict__ oa, u16* __restrict__ ob,
                       u16* __restrict__ oc, u16* __restrict__ od, int n4) {
    int i = blockIdx.x * blockDim.x + threadIdx.x;
    if (i >= n4) return;
    const float* src = (blockIdx.y == 0) ? a : (blockIdx.y == 1) ? b
                     : (blockIdx.y == 2) ? c : d;
    u16* dst = (blockIdx.y == 0) ? oa : (blockIdx.y == 1) ? ob
             : (blockIdx.y == 2) ? oc : od;
    float4 f = ((const float4*)src)[i];
    uint2 o;
    o.x = (u32)f2b(f.x) | ((u32)f2b(f.y) << 16);
    o.y = (u32)f2b(f.z) | ((u32)f2b(f.w) << 16);
    ((uint2*)dst)[i] = o;
}

// ---------------------------------------------------------------------------
// Angle suffix-sum (angle[t] = sum_{s>=t} emb[idx[s]]) in 2 phases; phase 2
// computes its own chunk-suffix (no serial scan dispatch) and emits packed
// bf16 {cos, sin}.
// ---------------------------------------------------------------------------
#define TT 1024
#define CC2 512
#define NCH 32
#define CL 32

__global__ void angle_partial(const int* __restrict__ idx, const float* __restrict__ emb,
                              float* __restrict__ partial) {
    int b = blockIdx.x >> 5, ch = blockIdx.x & 31;
    int c = threadIdx.x;               // 0..511
    float s = 0.f;
    int tb = ch * CL;
    for (int t = 0; t < CL; t++) {
        int row = idx[b * TT + tb + t];
        s += emb[(long long)row * CC2 + c];
    }
    partial[((long long)b * NCH + ch) * CC2 + c] = s;
}

__global__ void angle_final(const int* __restrict__ idx, const float* __restrict__ emb,
                            const float* __restrict__ partial,
                            u32* __restrict__ cossin) {
    int b = blockIdx.x >> 5, ch = blockIdx.x & 31;
    int c = threadIdx.x;
    // exclusive suffix over chunks after ch (same accumulation order as the
    // old serial scan: descending cc)
    float run = 0.f;
    for (int cc = NCH - 1; cc > ch; cc--)
        run += partial[((long long)b * NCH + cc) * CC2 + c];
    for (int t = CL - 1; t >= 0; t--) {
        int tt = ch * CL + t;
        int row = idx[b * TT + tt];
        run += emb[(long long)row * CC2 + c];
        float sn, cs;
        __sincosf(run, &sn, &cs);
        cossin[((long long)b * TT + tt) * CC2 + c] = (u32)f2b(cs) | ((u32)f2b(sn) << 16);
    }
}

// ---------------------------------------------------------------------------
extern "C" void kernel_launch(void* const* d_in, const int* in_sizes, int n_in,
                              void* d_out, int out_size, void* d_ws, size_t ws_size,
                              hipStream_t stream) {
    const int Bn = 16, T = 1024, C = 1024;
    const long long TC = (long long)T * C;
    const size_t nx = (size_t)Bn * T * C;          // 16,777,216
    const size_t npairs = nx / 2;                  // 8,388,608

    const float* x   = (const float*)d_in[0];
    const int*   idx = (const int*)d_in[1];
    const float* Wk  = (const float*)d_in[2];
    const float* bk  = (const float*)d_in[3];
    const float* Wq  = (const float*)d_in[4];
    const float* bq  = (const float*)d_in[5];
    const float* Wv  = (const float*)d_in[6];
    const float* bv  = (const float*)d_in[7];
    const float* Wp  = (const float*)d_in[8];
    const float* bp  = (const float*)d_in[9];
    const float* emb = (const float*)d_in[10];
    float* out = (float*)d_out;

    // one-time: allow 128 KiB dynamic LDS on the 256^2 kernels
    static bool s_attr = false;
    if (!s_attr) {
        auto* k0 = gemm256<0, 0>;
        auto* k1 = gemm256<1, 1>;
        auto* k2 = gemm256<2, 2>;
        auto* k3 = gemm256<3, 0>;
        (void)hipFuncSetAttribute(reinterpret_cast<const void*>(k0),
                                  hipFuncAttributeMaxDynamicSharedMemorySize, 131072);
        (void)hipFuncSetAttribute(reinterpret_cast<const void*>(k1),
                                  hipFuncAttributeMaxDynamicSharedMemorySize, 131072);
        (void)hipFuncSetAttribute(reinterpret_cast<const void*>(k2),
                                  hipFuncAttributeMaxDynamicSharedMemorySize, 131072);
        (void)hipFuncSetAttribute(reinterpret_cast<const void*>(k3),
                                  hipFuncAttributeMaxDynamicSharedMemorySize, 131072);
        s_attr = true;
    }

    // workspace (~171 MB)
    u16* xb  = (u16*)d_ws;          // x bf16; aliased as wei after QKV
    u16* kb  = xb + nx;             // k (rotated by QKV epilogue)
    u16* qb  = kb + nx;             // q (rotated); y after attn GEMM
    u16* vT  = qb + nx;             // v rotated+transposed [B][C][T]
    u32* cossin = (u32*)(vT + nx);  // [B][T][512] packed bf16 {cos,sin}
    u16* Wall = (u16*)(cossin + npairs);           // [3072][1024] = Wk|Wq|Wv
    u16* Wpb  = Wall + (size_t)3 * C * C;
    float* partial = (float*)(Wpb + (size_t)C * C);  // [B][32][512]
    u16* wei = xb;                  // alias (x dead after QKV)

    // 1) conversions to bf16
    f2b_kern<<<(int)(nx / 4 / 256), 256, 0, stream>>>(x, xb, (int)(nx / 4));
    f2b_w4<<<dim3(C * C / 4 / 256, 4), 256, 0, stream>>>(
        Wk, Wq, Wv, Wp, Wall, Wall + (size_t)C * C, Wall + (size_t)2 * C * C, Wpb,
        C * C / 4);

    // 2) angle suffix-sum -> packed cos/sin (2 dispatches; suffix computed
    //    in-kernel, serial scan dispatch removed)
    angle_partial<<<Bn * NCH, 512, 0, stream>>>(idx, emb, partial);
    angle_final<<<Bn * NCH, 512, 0, stream>>>(idx, emb, partial, cossin);

    // 3) fused QKV projection: M=16384, N=3072, K=1024; 64x12 tiles.
    gemm256<0, 0><<<768, 512, 131072, stream>>>(
        xb, 0, Wall, 0, kb, qb, vT, 0, bk, bq, bv, cossin,
        3 * C, C, 1.f, 12);

    // 4) wei = softplus(k @ q^T / 32), causal: 16 batches x 10 tril tiles
    gemm256<1, 1><<<160, 512, 131072, stream>>>(
        kb, TC, qb, TC, wei, nullptr, nullptr, (long long)T * T,
        nullptr, nullptr, nullptr, nullptr, T, C, 0.03125f, 0);

    // 5) attn = wei @ v, inverse-rotation epilogue -> y (qb);
    //    16 batches x 16 tiles, K truncated at (by+1)*256 (causal)
    gemm256<2, 2><<<256, 512, 131072, stream>>>(
        wei, (long long)T * T, vT, (long long)C * T, qb, nullptr, nullptr, TC,
        nullptr, nullptr, nullptr, cossin, C, T, 1.f, 0);

    // 6) final projection -> f32 out: 64x4 tiles.
    gemm256<3, 0><<<256, 512, 131072, stream>>>(
        qb, 0, Wpb, 0, out, nullptr, nullptr, 0, bp, nullptr, nullptr, nullptr,
        C, C, 1.f, 4);
}